// Round 1
// baseline (5723.549 us; speedup 1.0000x reference)
//
#include <hip/hip_runtime.h>
#include <hip/hip_fp16.h>
#include <stdint.h>

// ---------------- problem constants ----------------
#define T_STEPS 1000
#define BATCH   16
#define IFEAT   440
#define KPAD    448      // IFEAT padded to multiple of 32
#define HDIM    1024
#define PDIM    512
#define NWG     64       // workgroups in recurrent kernel (one per 16-wide h tile)

typedef _Float16 f16x8 __attribute__((ext_vector_type(8)));
typedef _Float16 f16x4 __attribute__((ext_vector_type(4)));
typedef float    f32x4 __attribute__((ext_vector_type(4)));

union H8u { f16x8 v; unsigned long long q[2]; };

// ---------------- workspace layout (bytes) ----------------
// flags[64] (64B stride each) + h double buffer must be zeroed each launch.
#define OFF_FLAGS 0u
#define OFF_HB    4096u                           // 2 * 16 * 1024 fp16 = 65536
#define OFF_XH    69632u                          // 1000*16*448 fp16   = 14,336,000
#define OFF_W4    (OFF_XH + 14336000u)            // 4*1024*448 fp16    = 3,670,016
#define OFF_TG    (OFF_W4 + 3670016u)             // 4*1024*512 fp16    = 4,194,304
#define OFF_WYT   (OFF_TG + 4194304u)             // 1024*512 fp16      = 1,048,576
#define OFF_M     (OFF_WYT + 1048576u)            // 4*1024*1024 fp16   = 8,388,608
#define OFF_GX    (OFF_M + 8388608u)              // 1000*4*1024*16 fp16= 131,072,000
// total ~163 MB

__device__ __forceinline__ float sigm_(float x)  { return 1.f / (1.f + __expf(-x)); }
__device__ __forceinline__ float tanh_(float x)  { return 1.f - 2.f / (1.f + __expf(2.f * x)); }

// ---------------- prep: x -> fp16 padded [t*16+b][448] ----------------
__global__ void prep_x(const float* __restrict__ x, _Float16* __restrict__ xh) {
    int idx = blockIdx.x * 256 + threadIdx.x;
    const int total = T_STEPS * BATCH * KPAD;
    for (; idx < total; idx += gridDim.x * 256) {
        int k = idx % KPAD;
        int row = idx / KPAD;                    // t*16 + b
        float v = (k < IFEAT) ? x[row * IFEAT + k] : 0.f;
        xh[idx] = (_Float16)v;
    }
}

// ---------------- prep: weights -> fp16 layouts ----------------
// W4[g][h][448] (input weights, padded), TG[g][h][512], WYT[hh][512] (wym transposed)
__global__ void prep_w(const float* __restrict__ wi, const float* __restrict__ wf,
                       const float* __restrict__ wo, const float* __restrict__ wc,
                       const float* __restrict__ ti, const float* __restrict__ tf,
                       const float* __restrict__ to_, const float* __restrict__ tc,
                       const float* __restrict__ wym,
                       _Float16* __restrict__ W4, _Float16* __restrict__ TG,
                       _Float16* __restrict__ WYT) {
    int tid = blockIdx.x * 256 + threadIdx.x;
    int stride = gridDim.x * 256;
    const float* const Wsrc[4] = {wi, wf, wo, wc};
    const float* const Tsrc[4] = {ti, tf, to_, tc};
    const int totW = 4 * HDIM * KPAD;
    for (int idx = tid; idx < totW; idx += stride) {
        int k = idx % KPAD; int gh = idx / KPAD;
        int h = gh % HDIM;  int g = gh / HDIM;
        W4[idx] = (_Float16)((k < IFEAT) ? Wsrc[g][h * IFEAT + k] : 0.f);
    }
    const int totT = 4 * HDIM * PDIM;
    for (int idx = tid; idx < totT; idx += stride) {
        int p = idx % PDIM; int gh = idx / PDIM;
        int h = gh % HDIM;  int g = gh / HDIM;
        TG[idx] = (_Float16)Tsrc[g][h * PDIM + p];
    }
    const int totY = HDIM * PDIM;
    for (int idx = tid; idx < totY; idx += stride) {
        int p = idx % PDIM; int hh = idx / PDIM;
        WYT[idx] = (_Float16)wym[p * HDIM + hh];   // transpose [512,1024] -> [1024,512]
    }
}

// ---------------- M_g = t_g @ wym  ([1024,512]x[512,1024] per gate) ----------------
// one 16x16 tile per wave; A = TG rows (m=h,k=p), B = WYT rows (n=hh,k=p)
__global__ __launch_bounds__(256) void mgemm(const _Float16* __restrict__ TG,
                                             const _Float16* __restrict__ WYT,
                                             _Float16* __restrict__ M) {
    int wave = threadIdx.x >> 6, l = threadIdx.x & 63;
    int lo = l & 15, quad = l >> 4;
    int tile = blockIdx.x * 4 + wave;            // 0..16383
    int g = tile >> 12;
    int ht = (tile >> 6) & 63;
    int hht = tile & 63;
    const _Float16* Ar = TG  + ((size_t)(g * HDIM + ht * 16 + lo)) * PDIM;
    const _Float16* Br = WYT + ((size_t)(hht * 16 + lo)) * PDIM;
    f32x4 acc = {0.f, 0.f, 0.f, 0.f};
#pragma unroll
    for (int cc = 0; cc < 16; ++cc) {
        f16x8 a = *(const f16x8*)(Ar + cc * 32 + quad * 8);
        f16x8 b = *(const f16x8*)(Br + cc * 32 + quad * 8);
        acc = __builtin_amdgcn_mfma_f32_16x16x32_f16(a, b, acc, 0, 0, 0);
    }
    _Float16* dst = M + (size_t)g * HDIM * HDIM;
#pragma unroll
    for (int r = 0; r < 4; ++r)
        dst[(size_t)(ht * 16 + quad * 4 + r) * HDIM + hht * 16 + lo] = (_Float16)acc[r];
}

// ---------------- phase 1: gx[t][g][htile][lane][r] = W4 . x + bias (fp16) ----------
// WG handles 4 timesteps; wave = gate; 2 interleaved h-tiles per inner iter.
#define TT 4
__global__ __launch_bounds__(256) void phase1(const _Float16* __restrict__ xh,
                                              const _Float16* __restrict__ W4,
                                              const float* __restrict__ bI,
                                              const float* __restrict__ bF,
                                              const float* __restrict__ bO,
                                              const float* __restrict__ bC,
                                              _Float16* __restrict__ GX) {
    __shared__ _Float16 sx[TT * 16 * 456];       // padded row stride 456 halfs
    const int t0 = blockIdx.x * TT;
    for (int c = threadIdx.x; c < TT * 16 * 56; c += 256) {
        int kc = c % 56, rowi = c / 56;
        *(f16x8*)(sx + rowi * 456 + kc * 8) =
            *(const f16x8*)(xh + ((size_t)(t0 * 16 + rowi)) * KPAD + kc * 8);
    }
    __syncthreads();
    const int wave = threadIdx.x >> 6, l = threadIdx.x & 63;
    const int lo = l & 15, quad = l >> 4;
    const int g = wave;
    const float* bias = (g == 0) ? bI : (g == 1) ? bF : (g == 2) ? bO : bC;
    for (int htp = 0; htp < 32; ++htp) {
        const int ht0 = htp * 2, ht1 = htp * 2 + 1;
        f16x8 A0[14], A1[14];
        const _Float16* Ar0 = W4 + ((size_t)(g * HDIM + ht0 * 16 + lo)) * KPAD;
        const _Float16* Ar1 = Ar0 + (size_t)16 * KPAD;
#pragma unroll
        for (int cc = 0; cc < 14; ++cc) {
            A0[cc] = *(const f16x8*)(Ar0 + cc * 32 + quad * 8);
            A1[cc] = *(const f16x8*)(Ar1 + cc * 32 + quad * 8);
        }
        float b0[4], b1[4];
#pragma unroll
        for (int r = 0; r < 4; ++r) {
            b0[r] = bias[ht0 * 16 + quad * 4 + r];
            b1[r] = bias[ht1 * 16 + quad * 4 + r];
        }
        for (int t = 0; t < TT; ++t) {
            f32x4 acc0 = {0.f, 0.f, 0.f, 0.f}, acc1 = {0.f, 0.f, 0.f, 0.f};
#pragma unroll
            for (int cc = 0; cc < 14; ++cc) {
                f16x8 b = *(const f16x8*)(sx + (t * 16 + lo) * 456 + cc * 32 + quad * 8);
                acc0 = __builtin_amdgcn_mfma_f32_16x16x32_f16(A0[cc], b, acc0, 0, 0, 0);
                acc1 = __builtin_amdgcn_mfma_f32_16x16x32_f16(A1[cc], b, acc1, 0, 0, 0);
            }
            size_t tbase = ((size_t)(t0 + t) * 4 + g) * 64;
            f16x4 h0, h1;
#pragma unroll
            for (int r = 0; r < 4; ++r) {
                h0[r] = (_Float16)(acc0[r] + b0[r]);
                h1[r] = (_Float16)(acc1[r] + b1[r]);
            }
            *(f16x4*)(GX + ((tbase + ht0) * 64 + l) * 4) = h0;
            *(f16x4*)(GX + ((tbase + ht1) * 64 + l) * 4) = h1;
        }
    }
}

// ---------------- persistent recurrent kernel ----------------
// 64 WGs x 256 thr. WG = h-tile (16 cols). Wave k = K-chunk [k*256,(k+1)*256) over hh,
// computing partials for all 4 gates. Wave 0 does cell update + h stores.
// Cross-WG sync: per-WG flag (release store) + wave-wide poll of all 64 flags.
__global__ __launch_bounds__(256, 1) void recur(const _Float16* __restrict__ GX,
                                                const _Float16* __restrict__ Mw,
                                                _Float16* __restrict__ HB,
                                                float* __restrict__ out,
                                                unsigned* __restrict__ flags) {
    const int tid = threadIdx.x, wave = tid >> 6, l = tid & 63;
    const int lo = l & 15, quad = l >> 4;
    const int ht = blockIdx.x;
    const int kbase = wave * 256;

    // register-resident A fragments of M: 4 gates x 8 K-frags (128 VGPRs)
    f16x8 A[4][8];
#pragma unroll
    for (int g = 0; g < 4; ++g) {
        const _Float16* Ar = Mw + ((size_t)g * HDIM + ht * 16 + lo) * HDIM + kbase;
#pragma unroll
        for (int cc = 0; cc < 8; ++cc)
            A[g][cc] = *(const f16x8*)(Ar + cc * 32 + quad * 8);
    }

    __shared__ float P[4][4][64][4];             // [kwave][gate][lane][r]
    f32x4 ct = {0.f, 0.f, 0.f, 0.f};

    f16x4 gxpA[4], gxpB[4];                      // gx prefetch ring (wave 0 only)
    if (wave == 0) {
#pragma unroll
        for (int g = 0; g < 4; ++g) {
            gxpA[g] = *(const f16x4*)(GX + ((((size_t)0 * 4 + g) * 64 + ht) * 64 + l) * 4);
            gxpB[g] = *(const f16x4*)(GX + ((((size_t)1 * 4 + g) * 64 + ht) * 64 + l) * 4);
        }
    }

    auto step = [&](int t, f16x4 (&gxc)[4]) {
        // ---- B fragments of h_{t-1}: agent-scope atomic 8B loads (cross-XCD coherent)
        const _Float16* hp = HB + (size_t)(t & 1) * BATCH * HDIM + (size_t)lo * HDIM + kbase;
        H8u B[8];
#pragma unroll
        for (int cc = 0; cc < 8; ++cc) {
            B[cc].q[0] = __hip_atomic_load((const unsigned long long*)(hp + cc * 32 + quad * 8),
                                           __ATOMIC_RELAXED, __HIP_MEMORY_SCOPE_AGENT);
            B[cc].q[1] = __hip_atomic_load((const unsigned long long*)(hp + cc * 32 + quad * 8 + 4),
                                           __ATOMIC_RELAXED, __HIP_MEMORY_SCOPE_AGENT);
        }
        f32x4 acc[4];
#pragma unroll
        for (int g = 0; g < 4; ++g) acc[g] = (f32x4){0.f, 0.f, 0.f, 0.f};
#pragma unroll
        for (int cc = 0; cc < 8; ++cc) {
#pragma unroll
            for (int g = 0; g < 4; ++g)
                acc[g] = __builtin_amdgcn_mfma_f32_16x16x32_f16(A[g][cc], B[cc].v, acc[g], 0, 0, 0);
        }
#pragma unroll
        for (int g = 0; g < 4; ++g)
            *(f32x4*)&P[wave][g][l][0] = acc[g];
        __syncthreads();

        if (wave == 0) {
            // ---- reduce K partials + gx, cell update for (h = ht*16+quad*4+r, b = lo)
            f32x4 pre[4];
#pragma unroll
            for (int g = 0; g < 4; ++g) {
                f32x4 s = *(const f32x4*)&P[0][g][l][0];
#pragma unroll
                for (int k = 1; k < 4; ++k) s = s + *(const f32x4*)&P[k][g][l][0];
                f16x4 gv = gxc[g];
#pragma unroll
                for (int r = 0; r < 4; ++r) s[r] += (float)gv[r];
                pre[g] = s;
            }
            f32x4 hv; f16x4 hh;
#pragma unroll
            for (int r = 0; r < 4; ++r) {
                float it = sigm_(pre[0][r]);
                float ft = sigm_(pre[1][r]);
                float ot = sigm_(pre[2][r]);
                float gt = tanh_(pre[3][r]);
                ct[r] = it * gt + ft * ct[r];
                float h = ot * tanh_(ct[r]);
                hv[r] = h; hh[r] = (_Float16)h;
            }
            // output h_t (f32) and fp16 staging for next step
            *(f32x4*)(out + ((size_t)t * BATCH + lo) * HDIM + ht * 16 + quad * 4) = hv;
            unsigned long long bits; __builtin_memcpy(&bits, &hh, 8);
            __hip_atomic_store((unsigned long long*)(HB + (size_t)((t + 1) & 1) * BATCH * HDIM +
                                                     (size_t)lo * HDIM + ht * 16 + quad * 4),
                               bits, __ATOMIC_RELAXED, __HIP_MEMORY_SCOPE_AGENT);
            if (l == 0)
                __hip_atomic_store(&flags[(unsigned)blockIdx.x * 16u], (unsigned)(t + 1),
                                   __ATOMIC_RELEASE, __HIP_MEMORY_SCOPE_AGENT);
        }
        if (wave == 0) {
            // ---- wave-wide barrier poll: lane l watches WG l's flag
            while (true) {
                unsigned v = __hip_atomic_load(&flags[(unsigned)l * 16u],
                                               __ATOMIC_RELAXED, __HIP_MEMORY_SCOPE_AGENT);
                if (__all((int)(v >= (unsigned)(t + 1)))) break;
                __builtin_amdgcn_s_sleep(1);
            }
            __builtin_amdgcn_fence(__ATOMIC_ACQUIRE, "agent");
            // ---- prefetch gx for t+2 into this parity's buffer
            int tp = (t + 2 < T_STEPS) ? (t + 2) : (T_STEPS - 1);
#pragma unroll
            for (int g = 0; g < 4; ++g)
                gxc[g] = *(const f16x4*)(GX + ((((size_t)tp * 4 + g) * 64 + ht) * 64 + l) * 4);
        }
        __syncthreads();
    };

    for (int t = 0; t < T_STEPS; t += 2) {
        step(t, gxpA);
        step(t + 1, gxpB);
    }
}

// ---------------- host ----------------
extern "C" void kernel_launch(void* const* d_in, const int* in_sizes, int n_in,
                              void* d_out, int out_size, void* d_ws, size_t ws_size,
                              hipStream_t stream) {
    const float* x    = (const float*)d_in[0];
    const float* wfxw = (const float*)d_in[1];
    const float* wfxb = (const float*)d_in[2];
    const float* wixw = (const float*)d_in[3];
    const float* wixb = (const float*)d_in[4];
    const float* woxw = (const float*)d_in[5];
    const float* woxb = (const float*)d_in[6];
    const float* wcxw = (const float*)d_in[7];
    const float* wcxb = (const float*)d_in[8];
    const float* tfyw = (const float*)d_in[9];
    const float* tiyw = (const float*)d_in[10];
    const float* toyw = (const float*)d_in[11];
    const float* tcyw = (const float*)d_in[12];
    const float* wymw = (const float*)d_in[13];

    char* ws = (char*)d_ws;
    unsigned*  flags = (unsigned*)(ws + OFF_FLAGS);
    _Float16*  HB    = (_Float16*)(ws + OFF_HB);
    _Float16*  XH    = (_Float16*)(ws + OFF_XH);
    _Float16*  W4    = (_Float16*)(ws + OFF_W4);
    _Float16*  TG    = (_Float16*)(ws + OFF_TG);
    _Float16*  WYT   = (_Float16*)(ws + OFF_WYT);
    _Float16*  Mw    = (_Float16*)(ws + OFF_M);
    _Float16*  GX    = (_Float16*)(ws + OFF_GX);
    float* out = (float*)d_out;

    // flags + h double-buffer must be zero at kernel start (ws is poisoned 0xAA)
    hipMemsetAsync(d_ws, 0, OFF_XH, stream);

    prep_x<<<4096, 256, 0, stream>>>(x, XH);
    prep_w<<<2048, 256, 0, stream>>>(wixw, wfxw, woxw, wcxw,
                                     tiyw, tfyw, toyw, tcyw, wymw,
                                     W4, TG, WYT);
    mgemm<<<4096, 256, 0, stream>>>(TG, WYT, Mw);
    phase1<<<250, 256, 0, stream>>>(XH, W4, wixb, wfxb, woxb, wcxb, GX);
    recur<<<NWG, 256, 0, stream>>>(GX, Mw, HB, out, flags);
}

// Round 2
// 4747.268 us; speedup vs baseline: 1.2057x; 1.2057x over previous
//
#include <hip/hip_runtime.h>
#include <hip/hip_fp16.h>
#include <stdint.h>

// ---------------- problem constants ----------------
#define T_STEPS 1000
#define BATCH   16
#define IFEAT   440
#define KPAD    448      // IFEAT padded to multiple of 32
#define HDIM    1024
#define PDIM    512
#define NWG     64       // workgroups in recurrent kernel (one per 16-wide h tile)

typedef _Float16 f16x8 __attribute__((ext_vector_type(8)));
typedef _Float16 f16x4 __attribute__((ext_vector_type(4)));
typedef float    f32x4 __attribute__((ext_vector_type(4)));
typedef uint32_t u32x4 __attribute__((ext_vector_type(4)));

union F16x8U { f16x8 v; u32x4 w; };

// ---------------- workspace layout (bytes) ----------------
#define OFF_HB    0u                              // 2 * 16 * 1024 fp16 = 65536
#define OFF_XH    65536u                          // 1000*16*448 fp16   = 14,336,000
#define OFF_W4    (OFF_XH + 14336000u)            // 4*1024*448 fp16    = 3,670,016
#define OFF_TG    (OFF_W4 + 3670016u)             // 4*1024*512 fp16    = 4,194,304
#define OFF_WYT   (OFF_TG + 4194304u)             // 1024*512 fp16      = 1,048,576
#define OFF_M     (OFF_WYT + 1048576u)            // 4*1024*1024 fp16   = 8,388,608
#define OFF_GX    (OFF_M + 8388608u)              // 1000*4*1024*16 fp16= 131,072,000

__device__ __forceinline__ float sigm_(float x)  { return 1.f / (1.f + __expf(-x)); }
__device__ __forceinline__ float tanh_(float x)  { return 1.f - 2.f / (1.f + __expf(2.f * x)); }

// ---------------- init: h double buffer with generation tags ----------------
// buffer0 (read at t=0, expect gen 0): 0x0000  (h=0, tag=0)
// buffer1 (read at t=1, expect gen 0): 0x0001  (tag=1 -> "not ready yet")
__global__ void init_hb(unsigned short* __restrict__ HB) {
    int i = blockIdx.x * 256 + threadIdx.x;      // 32768 total
    HB[i] = (i < BATCH * HDIM) ? (unsigned short)0x0000 : (unsigned short)0x0001;
}

// ---------------- prep: x -> fp16 padded [t*16+b][448] ----------------
__global__ void prep_x(const float* __restrict__ x, _Float16* __restrict__ xh) {
    int idx = blockIdx.x * 256 + threadIdx.x;
    const int total = T_STEPS * BATCH * KPAD;
    for (; idx < total; idx += gridDim.x * 256) {
        int k = idx % KPAD;
        int row = idx / KPAD;                    // t*16 + b
        float v = (k < IFEAT) ? x[row * IFEAT + k] : 0.f;
        xh[idx] = (_Float16)v;
    }
}

// ---------------- prep: weights -> fp16 layouts ----------------
__global__ void prep_w(const float* __restrict__ wi, const float* __restrict__ wf,
                       const float* __restrict__ wo, const float* __restrict__ wc,
                       const float* __restrict__ ti, const float* __restrict__ tf,
                       const float* __restrict__ to_, const float* __restrict__ tc,
                       const float* __restrict__ wym,
                       _Float16* __restrict__ W4, _Float16* __restrict__ TG,
                       _Float16* __restrict__ WYT) {
    int tid = blockIdx.x * 256 + threadIdx.x;
    int stride = gridDim.x * 256;
    const float* const Wsrc[4] = {wi, wf, wo, wc};
    const float* const Tsrc[4] = {ti, tf, to_, tc};
    const int totW = 4 * HDIM * KPAD;
    for (int idx = tid; idx < totW; idx += stride) {
        int k = idx % KPAD; int gh = idx / KPAD;
        int h = gh % HDIM;  int g = gh / HDIM;
        W4[idx] = (_Float16)((k < IFEAT) ? Wsrc[g][h * IFEAT + k] : 0.f);
    }
    const int totT = 4 * HDIM * PDIM;
    for (int idx = tid; idx < totT; idx += stride) {
        int p = idx % PDIM; int gh = idx / PDIM;
        int h = gh % HDIM;  int g = gh / HDIM;
        TG[idx] = (_Float16)Tsrc[g][h * PDIM + p];
    }
    const int totY = HDIM * PDIM;
    for (int idx = tid; idx < totY; idx += stride) {
        int p = idx % PDIM; int hh = idx / PDIM;
        WYT[idx] = (_Float16)wym[p * HDIM + hh];   // transpose [512,1024] -> [1024,512]
    }
}

// ---------------- M_g = t_g @ wym  ([1024,512]x[512,1024] per gate) ----------------
__global__ __launch_bounds__(256) void mgemm(const _Float16* __restrict__ TG,
                                             const _Float16* __restrict__ WYT,
                                             _Float16* __restrict__ M) {
    int wave = threadIdx.x >> 6, l = threadIdx.x & 63;
    int lo = l & 15, quad = l >> 4;
    int tile = blockIdx.x * 4 + wave;            // 0..16383
    int g = tile >> 12;
    int ht = (tile >> 6) & 63;
    int hht = tile & 63;
    const _Float16* Ar = TG  + ((size_t)(g * HDIM + ht * 16 + lo)) * PDIM;
    const _Float16* Br = WYT + ((size_t)(hht * 16 + lo)) * PDIM;
    f32x4 acc = {0.f, 0.f, 0.f, 0.f};
#pragma unroll
    for (int cc = 0; cc < 16; ++cc) {
        f16x8 a = *(const f16x8*)(Ar + cc * 32 + quad * 8);
        f16x8 b = *(const f16x8*)(Br + cc * 32 + quad * 8);
        acc = __builtin_amdgcn_mfma_f32_16x16x32_f16(a, b, acc, 0, 0, 0);
    }
    _Float16* dst = M + (size_t)g * HDIM * HDIM;
#pragma unroll
    for (int r = 0; r < 4; ++r)
        dst[(size_t)(ht * 16 + quad * 4 + r) * HDIM + hht * 16 + lo] = (_Float16)acc[r];
}

// ---------------- phase 1: gx[t][g][htile][lane][r] = W4 . x + bias (fp16) ----------
#define TT 4
__global__ __launch_bounds__(256) void phase1(const _Float16* __restrict__ xh,
                                              const _Float16* __restrict__ W4,
                                              const float* __restrict__ bI,
                                              const float* __restrict__ bF,
                                              const float* __restrict__ bO,
                                              const float* __restrict__ bC,
                                              _Float16* __restrict__ GX) {
    __shared__ _Float16 sx[TT * 16 * 456];
    const int t0 = blockIdx.x * TT;
    for (int c = threadIdx.x; c < TT * 16 * 56; c += 256) {
        int kc = c % 56, rowi = c / 56;
        *(f16x8*)(sx + rowi * 456 + kc * 8) =
            *(const f16x8*)(xh + ((size_t)(t0 * 16 + rowi)) * KPAD + kc * 8);
    }
    __syncthreads();
    const int wave = threadIdx.x >> 6, l = threadIdx.x & 63;
    const int lo = l & 15, quad = l >> 4;
    const int g = wave;
    const float* bias = (g == 0) ? bI : (g == 1) ? bF : (g == 2) ? bO : bC;
    for (int htp = 0; htp < 32; ++htp) {
        const int ht0 = htp * 2, ht1 = htp * 2 + 1;
        f16x8 A0[14], A1[14];
        const _Float16* Ar0 = W4 + ((size_t)(g * HDIM + ht0 * 16 + lo)) * KPAD;
        const _Float16* Ar1 = Ar0 + (size_t)16 * KPAD;
#pragma unroll
        for (int cc = 0; cc < 14; ++cc) {
            A0[cc] = *(const f16x8*)(Ar0 + cc * 32 + quad * 8);
            A1[cc] = *(const f16x8*)(Ar1 + cc * 32 + quad * 8);
        }
        float b0[4], b1[4];
#pragma unroll
        for (int r = 0; r < 4; ++r) {
            b0[r] = bias[ht0 * 16 + quad * 4 + r];
            b1[r] = bias[ht1 * 16 + quad * 4 + r];
        }
        for (int t = 0; t < TT; ++t) {
            f32x4 acc0 = {0.f, 0.f, 0.f, 0.f}, acc1 = {0.f, 0.f, 0.f, 0.f};
#pragma unroll
            for (int cc = 0; cc < 14; ++cc) {
                f16x8 b = *(const f16x8*)(sx + (t * 16 + lo) * 456 + cc * 32 + quad * 8);
                acc0 = __builtin_amdgcn_mfma_f32_16x16x32_f16(A0[cc], b, acc0, 0, 0, 0);
                acc1 = __builtin_amdgcn_mfma_f32_16x16x32_f16(A1[cc], b, acc1, 0, 0, 0);
            }
            size_t tbase = ((size_t)(t0 + t) * 4 + g) * 64;
            f16x4 h0, h1;
#pragma unroll
            for (int r = 0; r < 4; ++r) {
                h0[r] = (_Float16)(acc0[r] + b0[r]);
                h1[r] = (_Float16)(acc1[r] + b1[r]);
            }
            *(f16x4*)(GX + ((tbase + ht0) * 64 + l) * 4) = h0;
            *(f16x4*)(GX + ((tbase + ht1) * 64 + l) * 4) = h1;
        }
    }
}

// ---------------- persistent recurrent kernel (tagged-data sync) ----------------
// 64 WGs x 256 thr. WG = h-tile (16 cols). Wave k polls+loads its K-chunk
// [k*256,(k+1)*256) directly from MALL; the generation tag lives in the LSB of
// every fp16 h value, so the successful tagged load IS the synchronization (no
// flags, no fences, one __syncthreads per step). Double-buffer overwrite safety
// is transitive: a WG's step-t+2 store follows its 4 waves consuming all 64 WGs'
// step-t+1 tiles via the barrier. Wave0 stores fp16 h (+tags, MALL-direct);
// wave1 duplicates the cell update and stores f32 output (nontemporal), keeping
// the HBM store-ack off the h critical path.
__global__ __launch_bounds__(256, 1) void recur(const _Float16* __restrict__ GX,
                                                const _Float16* __restrict__ Mw,
                                                _Float16* __restrict__ HB,
                                                float* __restrict__ out) {
    const int tid = threadIdx.x, wave = tid >> 6, l = tid & 63;
    const int lo = l & 15, quad = l >> 4;
    const int ht = blockIdx.x;
    const int kbase = wave * 256;

    // register-resident A fragments of M: 4 gates x 8 K-frags (128 VGPRs)
    f16x8 A[4][8];
#pragma unroll
    for (int g = 0; g < 4; ++g) {
        const _Float16* Ar = Mw + ((size_t)g * HDIM + ht * 16 + lo) * HDIM + kbase;
#pragma unroll
        for (int cc = 0; cc < 8; ++cc)
            A[g][cc] = *(const f16x8*)(Ar + cc * 32 + quad * 8);
    }

    __shared__ float P[2][4][4][64][4];          // [par][kwave][gate][lane][r]
    f32x4 ct = {0.f, 0.f, 0.f, 0.f};             // waves 0/1 keep identical copies

    // gx prefetch ring, slot = t&1 (waves 0/1 only)
    f16x4 gxbuf[2][4];
    if (wave < 2) {
#pragma unroll
        for (int g = 0; g < 4; ++g) {
            gxbuf[0][g] = *(const f16x4*)(GX + ((((size_t)0 * 4 + g) * 64 + ht) * 64 + l) * 4);
            gxbuf[1][g] = *(const f16x4*)(GX + ((((size_t)1 * 4 + g) * 64 + ht) * 64 + l) * 4);
        }
    }

    // poll base (parity 0): this wave's B-fragment bytes for its K chunk
    const _Float16* hb0 = HB + (size_t)lo * HDIM + kbase + quad * 8;
    // h store base (parity 0), wave0's tile
    _Float16* hs0 = HB + (size_t)lo * HDIM + ht * 16 + quad * 4;

    auto step = [&](int t, int slot) {
        const int par = t & 1;
        const uint32_t expw = ((t >> 1) & 1) ? 0x00010001u : 0u;
        const uint64_t pollA = (uint64_t)(uintptr_t)(hb0 + (size_t)par * BATCH * HDIM);

        F16x8U B[8];
        // ---- tagged poll: MALL-direct loads, retry until all fp16 LSBs match gen
        while (true) {
            asm volatile(
                "global_load_dwordx4 %0, %8, off sc0 sc1\n\t"
                "global_load_dwordx4 %1, %8, off offset:64 sc0 sc1\n\t"
                "global_load_dwordx4 %2, %8, off offset:128 sc0 sc1\n\t"
                "global_load_dwordx4 %3, %8, off offset:192 sc0 sc1\n\t"
                "global_load_dwordx4 %4, %8, off offset:256 sc0 sc1\n\t"
                "global_load_dwordx4 %5, %8, off offset:320 sc0 sc1\n\t"
                "global_load_dwordx4 %6, %8, off offset:384 sc0 sc1\n\t"
                "global_load_dwordx4 %7, %8, off offset:448 sc0 sc1\n\t"
                "s_waitcnt vmcnt(0)"
                : "=&v"(B[0].w), "=&v"(B[1].w), "=&v"(B[2].w), "=&v"(B[3].w),
                  "=&v"(B[4].w), "=&v"(B[5].w), "=&v"(B[6].w), "=&v"(B[7].w)
                : "v"(pollA)
                : "memory");
            uint32_t bad = 0;
#pragma unroll
            for (int c = 0; c < 8; ++c)
#pragma unroll
                for (int j = 0; j < 4; ++j)
                    bad |= (B[c].w[j] ^ expw) & 0x00010001u;
            if (__all(bad == 0)) break;
        }

        f32x4 acc[4];
#pragma unroll
        for (int g = 0; g < 4; ++g) acc[g] = (f32x4){0.f, 0.f, 0.f, 0.f};
#pragma unroll
        for (int cc = 0; cc < 8; ++cc) {
#pragma unroll
            for (int g = 0; g < 4; ++g)
                acc[g] = __builtin_amdgcn_mfma_f32_16x16x32_f16(A[g][cc], B[cc].v, acc[g], 0, 0, 0);
        }
#pragma unroll
        for (int g = 0; g < 4; ++g)
            *(f32x4*)&P[par][wave][g][l][0] = acc[g];
        __syncthreads();

        if (wave < 2) {
            f32x4 pre[4];
#pragma unroll
            for (int g = 0; g < 4; ++g) {
                f32x4 s = *(const f32x4*)&P[par][0][g][l][0];
#pragma unroll
                for (int k = 1; k < 4; ++k) s = s + *(const f32x4*)&P[par][k][g][l][0];
                f16x4 gv = gxbuf[slot][g];
#pragma unroll
                for (int r = 0; r < 4; ++r) s[r] += (float)gv[r];
                pre[g] = s;
            }
            f32x4 hv; f16x4 hh;
#pragma unroll
            for (int r = 0; r < 4; ++r) {
                float it = sigm_(pre[0][r]);
                float ft = sigm_(pre[1][r]);
                float ot = sigm_(pre[2][r]);
                float gt = tanh_(pre[3][r]);
                ct[r] = it * gt + ft * ct[r];
                float h = ot * tanh_(ct[r]);
                hv[r] = h; hh[r] = (_Float16)h;
            }
            if (wave == 0) {
                // fp16 h with generation tag in every LSB -> MALL-direct store
                unsigned long long bits; __builtin_memcpy(&bits, &hh, 8);
                const unsigned long long TAG = 0x0001000100010001ULL;
                unsigned long long genw = (unsigned long long)(((t + 1) >> 1) & 1);
                bits = (bits & ~TAG) | (genw * TAG);
                uint64_t sA = (uint64_t)(uintptr_t)(hs0 + (size_t)((t + 1) & 1) * BATCH * HDIM);
                asm volatile("global_store_dwordx2 %0, %1, off sc0 sc1"
                             :: "v"(sA), "v"(bits) : "memory");
            } else {
                __builtin_nontemporal_store(hv,
                    (f32x4*)(out + ((size_t)t * BATCH + lo) * HDIM + ht * 16 + quad * 4));
            }
            // prefetch gx for t+2 into the slot just consumed (latency hides
            // under the next step's producer wait)
            int tp = (t + 2 < T_STEPS) ? (t + 2) : (T_STEPS - 1);
#pragma unroll
            for (int g = 0; g < 4; ++g)
                gxbuf[slot][g] = *(const f16x4*)(GX + ((((size_t)tp * 4 + g) * 64 + ht) * 64 + l) * 4);
        }
    };

    for (int t = 0; t < T_STEPS; t += 2) {
        step(t, 0);
        step(t + 1, 1);
    }
}

// ---------------- host ----------------
extern "C" void kernel_launch(void* const* d_in, const int* in_sizes, int n_in,
                              void* d_out, int out_size, void* d_ws, size_t ws_size,
                              hipStream_t stream) {
    const float* x    = (const float*)d_in[0];
    const float* wfxw = (const float*)d_in[1];
    const float* wfxb = (const float*)d_in[2];
    const float* wixw = (const float*)d_in[3];
    const float* wixb = (const float*)d_in[4];
    const float* woxw = (const float*)d_in[5];
    const float* woxb = (const float*)d_in[6];
    const float* wcxw = (const float*)d_in[7];
    const float* wcxb = (const float*)d_in[8];
    const float* tfyw = (const float*)d_in[9];
    const float* tiyw = (const float*)d_in[10];
    const float* toyw = (const float*)d_in[11];
    const float* tcyw = (const float*)d_in[12];
    const float* wymw = (const float*)d_in[13];

    char* ws = (char*)d_ws;
    _Float16*  HB    = (_Float16*)(ws + OFF_HB);
    _Float16*  XH    = (_Float16*)(ws + OFF_XH);
    _Float16*  W4    = (_Float16*)(ws + OFF_W4);
    _Float16*  TG    = (_Float16*)(ws + OFF_TG);
    _Float16*  WYT   = (_Float16*)(ws + OFF_WYT);
    _Float16*  Mw    = (_Float16*)(ws + OFF_M);
    _Float16*  GX    = (_Float16*)(ws + OFF_GX);
    float* out = (float*)d_out;

    init_hb<<<128, 256, 0, stream>>>((unsigned short*)HB);
    prep_x<<<4096, 256, 0, stream>>>(x, XH);
    prep_w<<<2048, 256, 0, stream>>>(wixw, wfxw, woxw, wcxw,
                                     tiyw, tfyw, toyw, tcyw, wymw,
                                     W4, TG, WYT);
    mgemm<<<4096, 256, 0, stream>>>(TG, WYT, Mw);
    phase1<<<250, 256, 0, stream>>>(XH, W4, wixb, wfxb, woxb, wcxb, GX);
    recur<<<NWG, 256, 0, stream>>>(GX, Mw, HB, out);
}